// Round 11
// baseline (115.215 us; speedup 1.0000x reference)
//
#include <hip/hip_runtime.h>
#include <hip/hip_bf16.h>
#include <math.h>

#define BB 2
#define TT 2048
#define CC 1024
#define HH 16
#define HS 64
#define NROWS (BB * TT)   // 4096
#define QTILES (TT / 64)  // 32

typedef __attribute__((ext_vector_type(8))) short short8v;   // 8 bf16 (4 VGPRs)
typedef __attribute__((ext_vector_type(4))) float f32x4;
typedef __attribute__((ext_vector_type(4))) unsigned int u32x4;
typedef unsigned short u16;

__device__ __forceinline__ u16 f2bf(float f) {
    return __builtin_bit_cast(u16, (__bf16)f);   // RNE hw cvt
}

// async global->LDS, 16B/lane; LDS dest = wave-uniform base + lane*16
__device__ __forceinline__ void glds16(const void* g, void* l) {
    __builtin_amdgcn_global_load_lds((__attribute__((address_space(1))) void*)g,
                                     (__attribute__((address_space(3))) void*)l, 16, 0, 0);
}
#define WAITV(N) asm volatile("s_waitcnt vmcnt(" #N ")" ::: "memory")
#define BAR() do { __builtin_amdgcn_s_barrier(); __builtin_amdgcn_sched_barrier(0); } while (0)

// cross-lane half-swaps (gfx950): after swap32(a,b): a = {a.lo32, b.lo32}, b = {a.hi32, b.hi32}
__device__ __forceinline__ void swap32(unsigned& a, unsigned& b) {
    asm volatile("v_permlane32_swap_b32 %0, %1" : "+v"(a), "+v"(b));
}
__device__ __forceinline__ void swap16(unsigned& a, unsigned& b) {
    asm volatile("v_permlane16_swap_b32 %0, %1" : "+v"(a), "+v"(b));
}

// ---------------- fused cast: x + all 4 weight matrices -> bf16 (one launch) ----------------
__global__ __launch_bounds__(256) void fsplit_kernel(const float* __restrict__ x,
                                                     const float* __restrict__ Wq, const float* __restrict__ Wk,
                                                     const float* __restrict__ Wv, const float* __restrict__ Wp,
                                                     u16* __restrict__ xh,
                                                     u16* __restrict__ wqk,   // d_out: [Wq_h|Wk_h]
                                                     u16* __restrict__ wv, u16* __restrict__ wp) {
    const size_t WC = (size_t)CC * CC;
    const int bid = blockIdx.x;
    const float* src; u16* dh; float sc = 1.f; int i;
    if (bid < 4096) {            // x: 4M elements / 4 per thread
        src = x; dh = xh; i = bid * 256 + threadIdx.x;
    } else {
        const int wsel = (bid - 4096) >> 10;
        i = ((bid - 4096) & 1023) * 256 + threadIdx.x;
        // fold 1/8 AND log2(e) into Wq: attn softmax then uses a single v_exp_f32 (exp2)
        if (wsel == 0)      { src = Wq; dh = wqk;      sc = 0.125f * 1.4426950408889634f; }
        else if (wsel == 1) { src = Wk; dh = wqk + WC; }
        else if (wsel == 2) { src = Wv; dh = wv; }
        else                { src = Wp; dh = wp; }
    }
    float4 v = ((const float4*)src)[i];
    v.x *= sc; v.y *= sc; v.z *= sc; v.w *= sc;
    ushort4 H;
    H.x = f2bf(v.x); H.y = f2bf(v.y); H.z = f2bf(v.z); H.w = f2bf(v.w);
    ((ushort4*)dh)[i] = H;
}

// ---------------- merged QK + V^T GEMM (one launch, 768 equal 128x128 blocks) ----------------
// bid < 512:  QK GEMM  A=xh [4096xK], B=wqk [2048xK] -> Qh/Kh bf16 (stride CC)
// bid >= 512: V^T GEMM A=wv [1024xK], B=xh  [4096xK] -> Vt[bh][d][t] bf16 + colsum TSg
__global__ __launch_bounds__(256) void qkv_kernel(const u16* __restrict__ xh, const u16* __restrict__ wqk,
                                                  const u16* __restrict__ wv,
                                                  u16* __restrict__ Qo, u16* __restrict__ Ko,
                                                  u16* __restrict__ VtO, float* __restrict__ TSg) {
    __shared__ u16 lA[2 * 4096], lB[2 * 4096];
    const int tid = threadIdx.x;
    const int lane = tid & 63, w = tid >> 6;
    const int wr = w >> 1, wc = w & 1;
    const int fr = lane & 15, fc = lane >> 4;
    const int K = CC;

    const int gbid = blockIdx.x;
    const bool isQK = gbid < 512;
    const int sub = isQK ? gbid : gbid - 512;
    const int nbx = isQK ? 16 : 32;
    const int nwg = isQK ? 512 : 256;
    const u16* __restrict__ A = isQK ? xh : wv;
    const u16* __restrict__ B = isQK ? wqk : xh;

    const int swz = (sub & 7) * (nwg >> 3) + (sub >> 3);
    const int bm = (swz / nbx) * 128, bn = (swz % nbx) * 128;

    f32x4 acc[4][4];
    #pragma unroll
    for (int i = 0; i < 4; ++i)
        #pragma unroll
        for (int j = 0; j < 4; ++j) acc[i][j] = (f32x4){0.f, 0.f, 0.f, 0.f};

    const int lrow = lane >> 2, lcs = lane & 3;
    const int rA0 = w * 16 + lrow, rA1 = rA0 + 64;
    const size_t aoff0 = (size_t)(bm + rA0) * K + (lcs ^ ((rA0 >> 1) & 3)) * 8;
    const size_t aoff1 = (size_t)(bm + rA1) * K + (lcs ^ ((rA1 >> 1) & 3)) * 8;
    const size_t boff0 = (size_t)(bn + rA0) * K + (lcs ^ ((rA0 >> 1) & 3)) * 8;
    const size_t boff1 = (size_t)(bn + rA1) * K + (lcs ^ ((rA1 >> 1) & 3)) * 8;
    const int d0 = w * 512, d1 = 2048 + w * 512;

    int aslot[4], bslot[4];
    #pragma unroll
    for (int mi = 0; mi < 4; ++mi) {
        int row = wr * 64 + mi * 16 + fr;
        aslot[mi] = row * 4 + (fc ^ ((row >> 1) & 3));
    }
    #pragma unroll
    for (int ni = 0; ni < 4; ++ni) {
        int col = wc * 64 + ni * 16 + fr;
        bslot[ni] = col * 4 + (fc ^ ((col >> 1) & 3));
    }

    auto STAGE = [&](int t, int buf) {
        const int k0 = t * 32;
        const int bo = buf * 4096;
        glds16(A + aoff0 + k0, lA + bo + d0);
        glds16(A + aoff1 + k0, lA + bo + d1);
        glds16(B + boff0 + k0, lB + bo + d0);
        glds16(B + boff1 + k0, lB + bo + d1);
    };

    const int nt = K >> 5;
    STAGE(0, 0);

    #pragma unroll 2
    for (int t = 0; t < nt; ++t) {
        const int cur = t & 1;
        BAR();   // prev iter's readers of buf[cur^1] are done -> safe to overwrite
        if (t + 1 < nt) { STAGE(t + 1, cur ^ 1); WAITV(4); }
        else            { WAITV(0); }

        const int co = cur * 512;
        short8v fa[4], fb[4];
        #pragma unroll
        for (int mi = 0; mi < 4; ++mi) fa[mi] = ((const short8v*)lA)[co + aslot[mi]];
        #pragma unroll
        for (int ni = 0; ni < 4; ++ni) fb[ni] = ((const short8v*)lB)[co + bslot[ni]];
        __builtin_amdgcn_s_setprio(1);
        #pragma unroll
        for (int mi = 0; mi < 4; ++mi)
            #pragma unroll
            for (int ni = 0; ni < 4; ++ni)
                acc[mi][ni] = __builtin_amdgcn_mfma_f32_16x16x32_bf16(fa[mi], fb[ni], acc[mi][ni], 0, 0, 0);
        __builtin_amdgcn_s_setprio(0);
    }

    const int fq = lane >> 4;
    if (isQK) {
        #pragma unroll
        for (int mi = 0; mi < 4; ++mi)
            #pragma unroll
            for (int ni = 0; ni < 4; ++ni)
                #pragma unroll
                for (int r = 0; r < 4; ++r) {
                    const int rg = bm + wr * 64 + mi * 16 + fq * 4 + r;
                    const int cg = bn + wc * 64 + ni * 16 + fr;
                    const u16 hh = f2bf(acc[mi][ni][r]);
                    if (cg < CC) Qo[(size_t)rg * CC + cg] = hh;
                    else         Ko[(size_t)rg * CC + cg - CC] = hh;
                }
    } else {
        // Vt output: rg = h*64+d (row of Wv), cg = b*2048+t
        #pragma unroll
        for (int mi = 0; mi < 4; ++mi)
            #pragma unroll
            for (int ni = 0; ni < 4; ++ni)
                #pragma unroll
                for (int r = 0; r < 4; ++r) {
                    const int rg = bm + wr * 64 + mi * 16 + fq * 4 + r;
                    const int cg = bn + wc * 64 + ni * 16 + fr;
                    const int bq = cg >> 11, tq = cg & 2047;
                    const int hq = rg >> 6, dq = rg & 63;
                    VtO[((size_t)((bq << 4) + hq) * HS + dq) * TT + tq] = f2bf(acc[mi][ni][r]);
                }
        // per-qt column sums: wave wc covers qt = ((bn + wc*64)&2047)>>6
        __syncthreads();                 // all LDS frag reads done -> reuse lA
        float* TSL = (float*)lA;         // 256 floats: [wc][row 0..127]
        #pragma unroll
        for (int mi = 0; mi < 4; ++mi)
            #pragma unroll
            for (int r = 0; r < 4; ++r) {
                float s = acc[mi][0][r] + acc[mi][1][r] + acc[mi][2][r] + acc[mi][3][r];
                s += __shfl_xor(s, 1); s += __shfl_xor(s, 2);
                s += __shfl_xor(s, 4); s += __shfl_xor(s, 8);
                if (fr == 0) TSL[wc * 128 + wr * 64 + mi * 16 + fq * 4 + r] = s;
            }
        __syncthreads();
        {
            const int wcq = tid >> 7, row = tid & 127;
            const int col0 = bn + wcq * 64;
            const int bq = col0 >> 11, qtv = (col0 & 2047) >> 6;
            const int bhh = (bq << 4) + ((bm + row) >> 6);
            const int dq = (bm + row) & 63;
            TSg[((size_t)bhh * QTILES + qtv) * 64 + dq] = TSL[tid];
        }
    }
}

// ---------------- proj GEMM (bf16 in, fp32 out), 128x128 tile = qkv QK-path template ----------------
__global__ __launch_bounds__(256) void gemm_proj(const u16* __restrict__ A, const u16* __restrict__ B,
                                                 float* __restrict__ O, int M, int N, int K) {
    __shared__ u16 lA[2 * 4096], lB[2 * 4096];
    const int tid = threadIdx.x;
    const int lane = tid & 63, w = tid >> 6;
    const int wr = w >> 1, wc = w & 1;
    const int fr = lane & 15, fc = lane >> 4;

    const int nbx = gridDim.x;
    const int bid = blockIdx.y * nbx + blockIdx.x;
    const int nwg = nbx * gridDim.y;
    const int swz = (bid & 7) * (nwg >> 3) + (bid >> 3);
    const int bm = (swz / nbx) * 128, bn = (swz % nbx) * 128;

    f32x4 acc[4][4];
    #pragma unroll
    for (int i = 0; i < 4; ++i)
        #pragma unroll
        for (int j = 0; j < 4; ++j) acc[i][j] = (f32x4){0.f, 0.f, 0.f, 0.f};

    const int lrow = lane >> 2, lcs = lane & 3;
    const int rA0 = w * 16 + lrow, rA1 = rA0 + 64;
    const size_t aoff0 = (size_t)(bm + rA0) * K + (lcs ^ ((rA0 >> 1) & 3)) * 8;
    const size_t aoff1 = (size_t)(bm + rA1) * K + (lcs ^ ((rA1 >> 1) & 3)) * 8;
    const size_t boff0 = (size_t)(bn + rA0) * K + (lcs ^ ((rA0 >> 1) & 3)) * 8;
    const size_t boff1 = (size_t)(bn + rA1) * K + (lcs ^ ((rA1 >> 1) & 3)) * 8;
    const int d0 = w * 512, d1 = 2048 + w * 512;

    int aslot[4], bslot[4];
    #pragma unroll
    for (int mi = 0; mi < 4; ++mi) {
        int row = wr * 64 + mi * 16 + fr;
        aslot[mi] = row * 4 + (fc ^ ((row >> 1) & 3));
    }
    #pragma unroll
    for (int ni = 0; ni < 4; ++ni) {
        int col = wc * 64 + ni * 16 + fr;
        bslot[ni] = col * 4 + (fc ^ ((col >> 1) & 3));
    }

    auto STAGE = [&](int t, int buf) {
        const int k0 = t * 32;
        const int bo = buf * 4096;
        glds16(A + aoff0 + k0, lA + bo + d0);
        glds16(A + aoff1 + k0, lA + bo + d1);
        glds16(B + boff0 + k0, lB + bo + d0);
        glds16(B + boff1 + k0, lB + bo + d1);
    };

    const int nt = K >> 5;
    STAGE(0, 0);

    #pragma unroll 2
    for (int t = 0; t < nt; ++t) {
        const int cur = t & 1;
        BAR();
        if (t + 1 < nt) { STAGE(t + 1, cur ^ 1); WAITV(4); }
        else            { WAITV(0); }

        const int co = cur * 512;
        short8v fa[4], fb[4];
        #pragma unroll
        for (int mi = 0; mi < 4; ++mi) fa[mi] = ((const short8v*)lA)[co + aslot[mi]];
        #pragma unroll
        for (int ni = 0; ni < 4; ++ni) fb[ni] = ((const short8v*)lB)[co + bslot[ni]];
        __builtin_amdgcn_s_setprio(1);
        #pragma unroll
        for (int mi = 0; mi < 4; ++mi)
            #pragma unroll
            for (int ni = 0; ni < 4; ++ni)
                acc[mi][ni] = __builtin_amdgcn_mfma_f32_16x16x32_bf16(fa[mi], fb[ni], acc[mi][ni], 0, 0, 0);
        __builtin_amdgcn_s_setprio(0);
    }

    const int fq = lane >> 4;
    #pragma unroll
    for (int mi = 0; mi < 4; ++mi)
        #pragma unroll
        for (int ni = 0; ni < 4; ++ni)
            #pragma unroll
            for (int r = 0; r < 4; ++r) {
                const int rg = bm + wr * 64 + mi * 16 + fq * 4 + r;
                const int cg = bn + wc * 64 + ni * 16 + fr;
                O[(size_t)rg * N + cg] = acc[mi][ni][r];
            }
}

// ---------------- MFMA flash attention (PROVEN 4-wave core): PAIRED q-tiles, K+V dbuf, 1 bar/iter ----------------
// 512 blocks = 32 bh x 16 p; block handles qt = {31-p, p} sequentially -> UNIFORM 33
// unit-iterations per block, 2 blocks/CU -> perfectly balanced makespan on every CU
// (the 1024-variable-block version had 52..80 units/CU spread).
// 4 waves; wave w owns q-rows [qt*64 + w*16, +16). Static max M=0; -U folded into y via
// negated causal ones MFMA on the diagonal tile; + in-kernel diag-INCLUSIVE suffix
// colsums for BOTH halves (one prologue pass over TSg).
// Sync (PROVEN R9/R10 protocol): per unit {WAITV(0); BAR; stage(next unit's tile, cur^1)};
// cross-half prefetch is just "next unit" = (qt_b, kt=0). The half-A epilogue (l-reduce,
// Y-write, y/l reset) is pure register/global work between barriers -- no LDS hazard.
__global__ __launch_bounds__(256, 4) void attn_kernel(const u16* __restrict__ Qh,
                                                      const u16* __restrict__ Kh,
                                                      const u16* __restrict__ Vt,
                                                      const float* __restrict__ TSg,
                                                      u16* __restrict__ Yh) {
    const int g = blockIdx.x;            // 512
    const int bh = (g & 7) + 8 * ((g >> 3) & 3);   // bh locked to one XCD
    const int p = g >> 5;                // 0..15
    const int qta = 31 - p, qtb = p;     // half A (big), half B (small); qtb < qta
    const int b = bh >> 4, h = bh & 15;
    const int tid = threadIdx.x;
    const int w = tid >> 6, lane = tid & 63;
    const int lx = lane & 15, hi4 = lane >> 4;

    __shared__ u16 Ksh[2 * 4096];    // 16KB: K dbuf
    __shared__ u16 Vsh[2 * 4096];    // 16KB: V dbuf
    __shared__ float stp4[2][4][64]; // suffix partials (both halves)
    __shared__ float stS[2][64];     // diag-inclusive suffix colsum per half

    const u16* Kg = Kh + (size_t)b * TT * CC + h * HS;
    const u16* Vg = Vt + (size_t)bh * HS * TT;

    // staging geometry: chunk s = w*64 + lane (+256); linear dest, source col pre-swizzled
    const int s0 = w * 64 + lane, s1 = 256 + w * 64 + lane;
    const int rr0 = s0 >> 3, gc0 = (s0 & 7) ^ (rr0 & 7);
    const int rr1 = s1 >> 3, gc1 = (s1 & 7) ^ (rr1 & 7);
    const int db0 = (w * 64) * 8, db1 = (256 + w * 64) * 8;
    const size_t kbase0 = (size_t)rr0 * CC + gc0 * 8;
    const size_t kbase1 = (size_t)rr1 * CC + gc1 * 8;
    const size_t vbase0 = (size_t)rr0 * TT + gc0 * 8;
    const size_t vbase1 = (size_t)rr1 * TT + gc1 * 8;

    auto stage = [&](int kt, int buf) {
        const size_t ko = (size_t)kt * 64 * CC;
        const int vo = kt * 64;
        const int bo = buf * 4096;
        glds16(Kg + ko + kbase0, Ksh + bo + db0);
        glds16(Kg + ko + kbase1, Ksh + bo + db1);
        glds16(Vg + vbase0 + vo, Vsh + bo + db0);
        glds16(Vg + vbase1 + vo, Vsh + bo + db1);
    };

    stage(0, 0);   // (half A, kt=0); DMA hides under the suffix prologue

    // ---- in-kernel suffix colsums (diag-inclusive), both halves in one strided pass ----
    {
        const int d = tid & 63, grp = tid >> 6;
        float pA = 0.f, pB = 0.f;
        for (int t2 = qtb + grp; t2 < QTILES; t2 += 4) {
            const float v = TSg[((size_t)bh * QTILES + t2) * 64 + d];
            pB += v;
            if (t2 >= qta) pA += v;
        }
        stp4[0][grp][d] = pA;
        stp4[1][grp][d] = pB;
        __syncthreads();
        if (tid < 128) {
            const int hf = tid >> 6, dd = tid & 63;
            stS[hf][dd] = stp4[hf][0][dd] + stp4[hf][1][dd] + stp4[hf][2][dd] + stp4[hf][3][dd];
        }
        __syncthreads();
    }

    // NEGATED causal-inclusive ones A-frags (intra-tile -> identical for both halves)
    short8v nones[2];
    #pragma unroll
    for (int k0 = 0; k0 < 2; ++k0)
        #pragma unroll
        for (int jj = 0; jj < 8; ++jj)
            nones[k0][jj] = (short)(((k0 * 32 + hi4 * 8 + jj) <= (w * 16 + lx)) ? 0xBF80 : 0);

    // preload Q fragments for both halves
    const size_t qoffA = (size_t)(b * TT + qta * 64 + w * 16 + lx) * CC + h * HS + hi4 * 8;
    const size_t qoffB = (size_t)(b * TT + qtb * 64 + w * 16 + lx) * CC + h * HS + hi4 * 8;
    short8v qfA[2], qfB[2];
    qfA[0] = *(const short8v*)(Qh + qoffA); qfA[1] = *(const short8v*)(Qh + qoffA + 32);
    qfB[0] = *(const short8v*)(Qh + qoffB); qfB[1] = *(const short8v*)(Qh + qoffB + 32);

    const f32x4 zero = {0.f, 0.f, 0.f, 0.f};
    f32x4 y4[4];
    float lsum = 0.f;
    #pragma unroll
    for (int dt = 0; dt < 4; ++dt) y4[dt] = zero;

    const int unitsA = qta + 1;
    const int total = unitsA + qtb + 1;   // = 33, uniform across all blocks
    int qt = qta;
    int hf = 0;
    int cur = 0;
    for (int u = 0; u < total; ++u) {
        const int kt = (u >= unitsA) ? (u - unitsA) : u;

        WAITV(0);   // own K/V DMA for this unit drained -> landed
        BAR();      // everyone's tiles visible; prev readers of buf[cur^1] done
        if (u + 1 < total) {
            const int nu = u + 1;
            const int nkt = (nu >= unitsA) ? (nu - unitsA) : nu;
            stage(nkt, cur ^ 1);
        }

        const int co = cur * 512;
        const bool diag = (kt == qt);

        // ---- QK^T (swapped: A=K, B=Q -> D = S^T) ----
        f32x4 s4[4];
        #pragma unroll
        for (int j = 0; j < 4; ++j) s4[j] = zero;
        __builtin_amdgcn_s_setprio(1);
        #pragma unroll
        for (int j = 0; j < 4; ++j) {
            const int keyr = j * 16 + lx;
            const int rb = keyr * 8, sw = keyr & 7;
            #pragma unroll
            for (int d0 = 0; d0 < 2; ++d0) {
                const short8v kb = ((const short8v*)Ksh)[co + rb + ((hi4 + 4 * d0) ^ sw)];
                const short8v qv = hf ? qfB[d0] : qfA[d0];
                s4[j] = __builtin_amdgcn_mfma_f32_16x16x32_bf16(kb, qv, s4[j], 0, 0, 0);
            }
        }
        __builtin_amdgcn_s_setprio(0);

        // ---- softmax (static M=0): lane holds P[key=j*16+hi4*4+r][q=lx] ----
        unsigned Wpk[4][2];   // [j][h]: bf16 pair of adjacent keys
        #pragma unroll
        for (int j = 0; j < 4; ++j) {
            float pv[4];
            #pragma unroll
            for (int r = 0; r < 4; ++r) {
                float e = __builtin_amdgcn_exp2f(s4[j][r]);
                if (diag && (j * 16 + hi4 * 4 + r) > (w * 16 + lx)) e = 0.f;
                lsum += e;
                pv[r] = e;
            }
            Wpk[j][0] = (unsigned)f2bf(pv[0]) | ((unsigned)f2bf(pv[1]) << 16);
            Wpk[j][1] = (unsigned)f2bf(pv[2]) | ((unsigned)f2bf(pv[3]) << 16);
        }
        // ---- in-register P transpose: 2-stage permlane butterfly ----
        #pragma unroll
        for (int j1 = 0; j1 < 2; ++j1)
            #pragma unroll
            for (int hh = 0; hh < 2; ++hh) {
                swap32(Wpk[2 * j1][hh], Wpk[2 * j1 + 1][hh]);
                swap16(Wpk[2 * j1][hh], Wpk[2 * j1 + 1][hh]);
            }
        short8v pa[2];
        #pragma unroll
        for (int k0 = 0; k0 < 2; ++k0) {
            u32x4 ah = {Wpk[2 * k0][0], Wpk[2 * k0][1], Wpk[2 * k0 + 1][0], Wpk[2 * k0 + 1][1]};
            pa[k0] = __builtin_bit_cast(short8v, ah);
        }

        // ---- PV (+ negated causal-ones on the diagonal tile); V(kt) proven landed ----
        __builtin_amdgcn_s_setprio(1);
        #pragma unroll
        for (int dt = 0; dt < 4; ++dt) {
            const int drow = dt * 16 + lx;
            const int rb = drow * 8, sw = drow & 7;
            #pragma unroll
            for (int k0 = 0; k0 < 2; ++k0) {
                const short8v vb = ((const short8v*)Vsh)[co + rb + ((hi4 + 4 * k0) ^ sw)];
                y4[dt] = __builtin_amdgcn_mfma_f32_16x16x32_bf16(pa[k0], vb, y4[dt], 0, 0, 0);
                if (diag)
                    y4[dt] = __builtin_amdgcn_mfma_f32_16x16x32_bf16(nones[k0], vb, y4[dt], 0, 0, 0);
            }
        }
        __builtin_amdgcn_s_setprio(0);

        if (diag) {
            // ---- epilogue for this half: l-reduce, add suffix colsum, normalize, write ----
            float ls = lsum;
            ls += __shfl_xor(ls, 16);
            ls += __shfl_xor(ls, 32);
            float l4[4];
            #pragma unroll
            for (int r = 0; r < 4; ++r) l4[r] = __shfl(ls, hi4 * 4 + r);

            #pragma unroll
            for (int dt = 0; dt < 4; ++dt) {
                const float st = stS[hf][dt * 16 + lx];
                #pragma unroll
                for (int r = 0; r < 4; ++r) {
                    const int t = qt * 64 + w * 16 + hi4 * 4 + r;
                    const float linv = 1.f / (l4[r] + (float)(TT - 1 - t));
                    const float yv = (y4[dt][r] + st) * linv;
                    const size_t off = (size_t)(b * TT + t) * CC + h * HS + dt * 16 + lx;
                    Yh[off] = f2bf(yv);
                }
            }
            // reset for half B
            #pragma unroll
            for (int dt = 0; dt < 4; ++dt) y4[dt] = zero;
            lsum = 0.f;
            qt = qtb;
            hf = 1;
        }

        cur ^= 1;
    }
}

// ---------------- launch ----------------
extern "C" void kernel_launch(void* const* d_in, const int* in_sizes, int n_in,
                              void* d_out, int out_size, void* d_ws, size_t ws_size,
                              hipStream_t stream) {
    const float* x  = (const float*)d_in[0];
    const float* Wq = (const float*)d_in[1];
    const float* Wk = (const float*)d_in[2];
    const float* Wv = (const float*)d_in[3];
    const float* Wp = (const float*)d_in[4];
    float* out = (float*)d_out;

    char* ws = (char*)d_ws;
    // [0,8MB): x bf16; after qkv x is dead -> Y bf16
    u16* xh = (u16*)ws;
    u16* Yh = xh;
    // [16,24MB): Q bf16; [32,40MB): K bf16
    u16* Qh = (u16*)(ws + (16u << 20));
    u16* Kh = (u16*)(ws + (32u << 20));
    // [48,50MB): Wv bf16; [52,+256KB): TSg; [56,58MB): Wp bf16
    u16* wv = (u16*)(ws + (48u << 20));
    float* TSg = (float*)(ws + (52u << 20));
    u16* wp = (u16*)(ws + (56u << 20));
    // d_out (16MB): wqk [0,4MB), Vt [4,12MB) (both dead before proj overwrites)
    u16* wqk = (u16*)out;
    u16* Vth = (u16*)((char*)out + (4u << 20));

    fsplit_kernel<<<8192, 256, 0, stream>>>(x, Wq, Wk, Wv, Wp, xh, wqk, wv, wp);

    // merged QK GEMM (512 blocks) + V^T GEMM (256 blocks)
    qkv_kernel<<<768, 256, 0, stream>>>(xh, wqk, wv, Qh, Kh, Vth, TSg);

    attn_kernel<<<512, 256, 0, stream>>>(Qh, Kh, Vth, TSg, Yh);

    // output projection, 128x128 tile, 256 equal blocks (overwrites d_out; wqk/Vt dead)
    gemm_proj<<<dim3(CC / 128, NROWS / 128), 256, 0, stream>>>(Yh, wp, out, NROWS, CC, CC);
}

// Round 12
// 104.462 us; speedup vs baseline: 1.1029x; 1.1029x over previous
//
#include <hip/hip_runtime.h>
#include <hip/hip_bf16.h>
#include <math.h>

#define BB 2
#define TT 2048
#define CC 1024
#define HH 16
#define HS 64
#define NROWS (BB * TT)   // 4096
#define QTILES (TT / 64)  // 32

typedef __attribute__((ext_vector_type(8))) short short8v;   // 8 bf16 (4 VGPRs)
typedef __attribute__((ext_vector_type(4))) float f32x4;
typedef __attribute__((ext_vector_type(4))) unsigned int u32x4;
typedef unsigned short u16;

__device__ __forceinline__ u16 f2bf(float f) {
    return __builtin_bit_cast(u16, (__bf16)f);   // RNE hw cvt
}

// async global->LDS, 16B/lane; LDS dest = wave-uniform base + lane*16
__device__ __forceinline__ void glds16(const void* g, void* l) {
    __builtin_amdgcn_global_load_lds((__attribute__((address_space(1))) void*)g,
                                     (__attribute__((address_space(3))) void*)l, 16, 0, 0);
}
#define WAITV(N) asm volatile("s_waitcnt vmcnt(" #N ")" ::: "memory")
#define BAR() do { __builtin_amdgcn_s_barrier(); __builtin_amdgcn_sched_barrier(0); } while (0)

// cross-lane half-swaps (gfx950): after swap32(a,b): a = {a.lo32, b.lo32}, b = {a.hi32, b.hi32}
__device__ __forceinline__ void swap32(unsigned& a, unsigned& b) {
    asm volatile("v_permlane32_swap_b32 %0, %1" : "+v"(a), "+v"(b));
}
__device__ __forceinline__ void swap16(unsigned& a, unsigned& b) {
    asm volatile("v_permlane16_swap_b32 %0, %1" : "+v"(a), "+v"(b));
}

// ---------------- fused cast: x + all 4 weight matrices -> bf16 (one launch) ----------------
__global__ __launch_bounds__(256) void fsplit_kernel(const float* __restrict__ x,
                                                     const float* __restrict__ Wq, const float* __restrict__ Wk,
                                                     const float* __restrict__ Wv, const float* __restrict__ Wp,
                                                     u16* __restrict__ xh,
                                                     u16* __restrict__ wqk,   // d_out: [Wq_h|Wk_h]
                                                     u16* __restrict__ wv, u16* __restrict__ wp) {
    const size_t WC = (size_t)CC * CC;
    const int bid = blockIdx.x;
    const float* src; u16* dh; float sc = 1.f; int i;
    if (bid < 4096) {            // x: 4M elements / 4 per thread
        src = x; dh = xh; i = bid * 256 + threadIdx.x;
    } else {
        const int wsel = (bid - 4096) >> 10;
        i = ((bid - 4096) & 1023) * 256 + threadIdx.x;
        // fold 1/8 AND log2(e) into Wq: attn softmax then uses a single v_exp_f32 (exp2)
        if (wsel == 0)      { src = Wq; dh = wqk;      sc = 0.125f * 1.4426950408889634f; }
        else if (wsel == 1) { src = Wk; dh = wqk + WC; }
        else if (wsel == 2) { src = Wv; dh = wv; }
        else                { src = Wp; dh = wp; }
    }
    float4 v = ((const float4*)src)[i];
    v.x *= sc; v.y *= sc; v.z *= sc; v.w *= sc;
    ushort4 H;
    H.x = f2bf(v.x); H.y = f2bf(v.y); H.z = f2bf(v.z); H.w = f2bf(v.w);
    ((ushort4*)dh)[i] = H;
}

// ---------------- merged QK + V^T GEMM (one launch, 768 equal 128x128 blocks) ----------------
// bid < 512:  QK GEMM  A=xh [4096xK], B=wqk [2048xK] -> Qh/Kh bf16 (stride CC)
// bid >= 512: V^T GEMM A=wv [1024xK], B=xh  [4096xK] -> Vt[bh][d][t] bf16 + colsum TSg
__global__ __launch_bounds__(256) void qkv_kernel(const u16* __restrict__ xh, const u16* __restrict__ wqk,
                                                  const u16* __restrict__ wv,
                                                  u16* __restrict__ Qo, u16* __restrict__ Ko,
                                                  u16* __restrict__ VtO, float* __restrict__ TSg) {
    __shared__ u16 lA[2 * 4096], lB[2 * 4096];
    const int tid = threadIdx.x;
    const int lane = tid & 63, w = tid >> 6;
    const int wr = w >> 1, wc = w & 1;
    const int fr = lane & 15, fc = lane >> 4;
    const int K = CC;

    const int gbid = blockIdx.x;
    const bool isQK = gbid < 512;
    const int sub = isQK ? gbid : gbid - 512;
    const int nbx = isQK ? 16 : 32;
    const int nwg = isQK ? 512 : 256;
    const u16* __restrict__ A = isQK ? xh : wv;
    const u16* __restrict__ B = isQK ? wqk : xh;

    const int swz = (sub & 7) * (nwg >> 3) + (sub >> 3);
    const int bm = (swz / nbx) * 128, bn = (swz % nbx) * 128;

    f32x4 acc[4][4];
    #pragma unroll
    for (int i = 0; i < 4; ++i)
        #pragma unroll
        for (int j = 0; j < 4; ++j) acc[i][j] = (f32x4){0.f, 0.f, 0.f, 0.f};

    const int lrow = lane >> 2, lcs = lane & 3;
    const int rA0 = w * 16 + lrow, rA1 = rA0 + 64;
    const size_t aoff0 = (size_t)(bm + rA0) * K + (lcs ^ ((rA0 >> 1) & 3)) * 8;
    const size_t aoff1 = (size_t)(bm + rA1) * K + (lcs ^ ((rA1 >> 1) & 3)) * 8;
    const size_t boff0 = (size_t)(bn + rA0) * K + (lcs ^ ((rA0 >> 1) & 3)) * 8;
    const size_t boff1 = (size_t)(bn + rA1) * K + (lcs ^ ((rA1 >> 1) & 3)) * 8;
    const int d0 = w * 512, d1 = 2048 + w * 512;

    int aslot[4], bslot[4];
    #pragma unroll
    for (int mi = 0; mi < 4; ++mi) {
        int row = wr * 64 + mi * 16 + fr;
        aslot[mi] = row * 4 + (fc ^ ((row >> 1) & 3));
    }
    #pragma unroll
    for (int ni = 0; ni < 4; ++ni) {
        int col = wc * 64 + ni * 16 + fr;
        bslot[ni] = col * 4 + (fc ^ ((col >> 1) & 3));
    }

    auto STAGE = [&](int t, int buf) {
        const int k0 = t * 32;
        const int bo = buf * 4096;
        glds16(A + aoff0 + k0, lA + bo + d0);
        glds16(A + aoff1 + k0, lA + bo + d1);
        glds16(B + boff0 + k0, lB + bo + d0);
        glds16(B + boff1 + k0, lB + bo + d1);
    };

    const int nt = K >> 5;
    STAGE(0, 0);

    #pragma unroll 2
    for (int t = 0; t < nt; ++t) {
        const int cur = t & 1;
        BAR();   // prev iter's readers of buf[cur^1] are done -> safe to overwrite
        if (t + 1 < nt) { STAGE(t + 1, cur ^ 1); WAITV(4); }
        else            { WAITV(0); }

        const int co = cur * 512;
        short8v fa[4], fb[4];
        #pragma unroll
        for (int mi = 0; mi < 4; ++mi) fa[mi] = ((const short8v*)lA)[co + aslot[mi]];
        #pragma unroll
        for (int ni = 0; ni < 4; ++ni) fb[ni] = ((const short8v*)lB)[co + bslot[ni]];
        __builtin_amdgcn_s_setprio(1);
        #pragma unroll
        for (int mi = 0; mi < 4; ++mi)
            #pragma unroll
            for (int ni = 0; ni < 4; ++ni)
                acc[mi][ni] = __builtin_amdgcn_mfma_f32_16x16x32_bf16(fa[mi], fb[ni], acc[mi][ni], 0, 0, 0);
        __builtin_amdgcn_s_setprio(0);
    }

    const int fq = lane >> 4;
    if (isQK) {
        #pragma unroll
        for (int mi = 0; mi < 4; ++mi)
            #pragma unroll
            for (int ni = 0; ni < 4; ++ni)
                #pragma unroll
                for (int r = 0; r < 4; ++r) {
                    const int rg = bm + wr * 64 + mi * 16 + fq * 4 + r;
                    const int cg = bn + wc * 64 + ni * 16 + fr;
                    const u16 hh = f2bf(acc[mi][ni][r]);
                    if (cg < CC) Qo[(size_t)rg * CC + cg] = hh;
                    else         Ko[(size_t)rg * CC + cg - CC] = hh;
                }
    } else {
        // Vt output: rg = h*64+d (row of Wv), cg = b*2048+t
        #pragma unroll
        for (int mi = 0; mi < 4; ++mi)
            #pragma unroll
            for (int ni = 0; ni < 4; ++ni)
                #pragma unroll
                for (int r = 0; r < 4; ++r) {
                    const int rg = bm + wr * 64 + mi * 16 + fq * 4 + r;
                    const int cg = bn + wc * 64 + ni * 16 + fr;
                    const int bq = cg >> 11, tq = cg & 2047;
                    const int hq = rg >> 6, dq = rg & 63;
                    VtO[((size_t)((bq << 4) + hq) * HS + dq) * TT + tq] = f2bf(acc[mi][ni][r]);
                }
        // per-qt column sums: wave wc covers qt = ((bn + wc*64)&2047)>>6
        __syncthreads();                 // all LDS frag reads done -> reuse lA
        float* TSL = (float*)lA;         // 256 floats: [wc][row 0..127]
        #pragma unroll
        for (int mi = 0; mi < 4; ++mi)
            #pragma unroll
            for (int r = 0; r < 4; ++r) {
                float s = acc[mi][0][r] + acc[mi][1][r] + acc[mi][2][r] + acc[mi][3][r];
                s += __shfl_xor(s, 1); s += __shfl_xor(s, 2);
                s += __shfl_xor(s, 4); s += __shfl_xor(s, 8);
                if (fr == 0) TSL[wc * 128 + wr * 64 + mi * 16 + fq * 4 + r] = s;
            }
        __syncthreads();
        {
            const int wcq = tid >> 7, row = tid & 127;
            const int col0 = bn + wcq * 64;
            const int bq = col0 >> 11, qtv = (col0 & 2047) >> 6;
            const int bhh = (bq << 4) + ((bm + row) >> 6);
            const int dq = (bm + row) & 63;
            TSg[((size_t)bhh * QTILES + qtv) * 64 + dq] = TSL[tid];
        }
    }
}

// ---------------- proj GEMM (bf16 in, fp32 out), 128x128 tile = qkv QK-path template ----------------
__global__ __launch_bounds__(256) void gemm_proj(const u16* __restrict__ A, const u16* __restrict__ B,
                                                 float* __restrict__ O, int M, int N, int K) {
    __shared__ u16 lA[2 * 4096], lB[2 * 4096];
    const int tid = threadIdx.x;
    const int lane = tid & 63, w = tid >> 6;
    const int wr = w >> 1, wc = w & 1;
    const int fr = lane & 15, fc = lane >> 4;

    const int nbx = gridDim.x;
    const int bid = blockIdx.y * nbx + blockIdx.x;
    const int nwg = nbx * gridDim.y;
    const int swz = (bid & 7) * (nwg >> 3) + (bid >> 3);
    const int bm = (swz / nbx) * 128, bn = (swz % nbx) * 128;

    f32x4 acc[4][4];
    #pragma unroll
    for (int i = 0; i < 4; ++i)
        #pragma unroll
        for (int j = 0; j < 4; ++j) acc[i][j] = (f32x4){0.f, 0.f, 0.f, 0.f};

    const int lrow = lane >> 2, lcs = lane & 3;
    const int rA0 = w * 16 + lrow, rA1 = rA0 + 64;
    const size_t aoff0 = (size_t)(bm + rA0) * K + (lcs ^ ((rA0 >> 1) & 3)) * 8;
    const size_t aoff1 = (size_t)(bm + rA1) * K + (lcs ^ ((rA1 >> 1) & 3)) * 8;
    const size_t boff0 = (size_t)(bn + rA0) * K + (lcs ^ ((rA0 >> 1) & 3)) * 8;
    const size_t boff1 = (size_t)(bn + rA1) * K + (lcs ^ ((rA1 >> 1) & 3)) * 8;
    const int d0 = w * 512, d1 = 2048 + w * 512;

    int aslot[4], bslot[4];
    #pragma unroll
    for (int mi = 0; mi < 4; ++mi) {
        int row = wr * 64 + mi * 16 + fr;
        aslot[mi] = row * 4 + (fc ^ ((row >> 1) & 3));
    }
    #pragma unroll
    for (int ni = 0; ni < 4; ++ni) {
        int col = wc * 64 + ni * 16 + fr;
        bslot[ni] = col * 4 + (fc ^ ((col >> 1) & 3));
    }

    auto STAGE = [&](int t, int buf) {
        const int k0 = t * 32;
        const int bo = buf * 4096;
        glds16(A + aoff0 + k0, lA + bo + d0);
        glds16(A + aoff1 + k0, lA + bo + d1);
        glds16(B + boff0 + k0, lB + bo + d0);
        glds16(B + boff1 + k0, lB + bo + d1);
    };

    const int nt = K >> 5;
    STAGE(0, 0);

    #pragma unroll 2
    for (int t = 0; t < nt; ++t) {
        const int cur = t & 1;
        BAR();
        if (t + 1 < nt) { STAGE(t + 1, cur ^ 1); WAITV(4); }
        else            { WAITV(0); }

        const int co = cur * 512;
        short8v fa[4], fb[4];
        #pragma unroll
        for (int mi = 0; mi < 4; ++mi) fa[mi] = ((const short8v*)lA)[co + aslot[mi]];
        #pragma unroll
        for (int ni = 0; ni < 4; ++ni) fb[ni] = ((const short8v*)lB)[co + bslot[ni]];
        __builtin_amdgcn_s_setprio(1);
        #pragma unroll
        for (int mi = 0; mi < 4; ++mi)
            #pragma unroll
            for (int ni = 0; ni < 4; ++ni)
                acc[mi][ni] = __builtin_amdgcn_mfma_f32_16x16x32_bf16(fa[mi], fb[ni], acc[mi][ni], 0, 0, 0);
        __builtin_amdgcn_s_setprio(0);
    }

    const int fq = lane >> 4;
    #pragma unroll
    for (int mi = 0; mi < 4; ++mi)
        #pragma unroll
        for (int ni = 0; ni < 4; ++ni)
            #pragma unroll
            for (int r = 0; r < 4; ++r) {
                const int rg = bm + wr * 64 + mi * 16 + fq * 4 + r;
                const int cg = bn + wc * 64 + ni * 16 + fr;
                O[(size_t)rg * N + cg] = acc[mi][ni][r];
            }
}

// ---------------- MFMA flash attention (PROVEN R10 core): 1 q-tile/block, K+V dbuf, 1 bar/iter ----------------
// 1024 blocks = 32 bh x 32 qt, 4 blocks/CU (full residency). With ALL blocks co-resident
// (no backfill), makespan = max per-CU sum of (qt+1). Under round-robin dispatch CU c gets
// qt-indices {a, a+8, a+16, a+24}, a=(c>>5)&7; the qtseq below makes every such quadruple
// sum to the uniform 62: qtseq = {31-a, 16+a, 15-a, a} -> balanced makespan at FULL
// occupancy (R11's pairing balanced but halved residency -> 49us; this keeps both).
// 4 waves; wave w owns q-rows [w*16, +16). Static max M=0; -U folded via negated causal
// ones MFMA on the diagonal tile; + in-kernel diag-INCLUSIVE suffix colsum.
// Sync (PROVEN): per iter {WAITV(0); BAR; stage(kt+1, cur^1)}.
__global__ __launch_bounds__(256, 4) void attn_kernel(const u16* __restrict__ Qh,
                                                      const u16* __restrict__ Kh,
                                                      const u16* __restrict__ Vt,
                                                      const float* __restrict__ TSg,
                                                      u16* __restrict__ Yh) {
    const int g = blockIdx.x;            // 1024
    const int bh = (g & 7) + 8 * ((g >> 3) & 3);   // bh locked to one XCD
    const int idx = g >> 5;              // 0..31
    const int a = idx & 7, j4 = idx >> 3;
    const int qt = (j4 == 0) ? (31 - a) : (j4 == 1) ? (16 + a) : (j4 == 2) ? (15 - a) : a;
    const int b = bh >> 4, h = bh & 15;
    const int tid = threadIdx.x;
    const int w = tid >> 6, lane = tid & 63;
    const int lx = lane & 15, hi4 = lane >> 4;

    __shared__ u16 Ksh[2 * 4096];   // 16KB: K dbuf
    __shared__ u16 Vsh[2 * 4096];   // 16KB: V dbuf
    __shared__ float stp4[4][64];   // suffix partials
    __shared__ float stS[64];       // suffix colsum for this qt (diag-inclusive)

    const u16* Kg = Kh + (size_t)b * TT * CC + h * HS;
    const u16* Vg = Vt + (size_t)bh * HS * TT;

    // staging geometry: chunk s = w*64 + lane (+256); linear dest, source col pre-swizzled
    const int s0 = w * 64 + lane, s1 = 256 + w * 64 + lane;
    const int rr0 = s0 >> 3, gc0 = (s0 & 7) ^ (rr0 & 7);
    const int rr1 = s1 >> 3, gc1 = (s1 & 7) ^ (rr1 & 7);
    const int db0 = (w * 64) * 8, db1 = (256 + w * 64) * 8;
    const size_t kbase0 = (size_t)rr0 * CC + gc0 * 8;
    const size_t kbase1 = (size_t)rr1 * CC + gc1 * 8;
    const size_t vbase0 = (size_t)rr0 * TT + gc0 * 8;
    const size_t vbase1 = (size_t)rr1 * TT + gc1 * 8;

    auto stage = [&](int kt, int buf) {
        const size_t ko = (size_t)kt * 64 * CC;
        const int vo = kt * 64;
        const int bo = buf * 4096;
        glds16(Kg + ko + kbase0, Ksh + bo + db0);
        glds16(Kg + ko + kbase1, Ksh + bo + db1);
        glds16(Vg + vbase0 + vo, Vsh + bo + db0);
        glds16(Vg + vbase1 + vo, Vsh + bo + db1);
    };

    stage(0, 0);   // tile-0 DMA hides under the suffix prologue

    // ---- in-kernel suffix colsum (diag-inclusive): stS = sum_{t2 >= qt} TSg[bh][t2] ----
    {
        const int d = tid & 63, grp = tid >> 6;
        float part = 0.f;
        for (int t2 = qt + grp; t2 < QTILES; t2 += 4)
            part += TSg[((size_t)bh * QTILES + t2) * 64 + d];
        stp4[grp][d] = part;
        __syncthreads();
        if (tid < 64) stS[tid] = stp4[0][tid] + stp4[1][tid] + stp4[2][tid] + stp4[3][tid];
        __syncthreads();
    }

    // NEGATED causal-inclusive ones A-frags (fold -U into y on the diagonal tile)
    short8v nones[2];
    #pragma unroll
    for (int k0 = 0; k0 < 2; ++k0)
        #pragma unroll
        for (int jj = 0; jj < 8; ++jj)
            nones[k0][jj] = (short)(((k0 * 32 + hi4 * 8 + jj) <= (w * 16 + lx)) ? 0xBF80 : 0);

    const size_t qoff = (size_t)(b * TT + qt * 64 + w * 16 + lx) * CC + h * HS + hi4 * 8;
    short8v qf[2];
    qf[0] = *(const short8v*)(Qh + qoff); qf[1] = *(const short8v*)(Qh + qoff + 32);

    const f32x4 zero = {0.f, 0.f, 0.f, 0.f};
    f32x4 y4[4];
    float lsum = 0.f;
    #pragma unroll
    for (int dt = 0; dt < 4; ++dt) y4[dt] = zero;

    int cur = 0;
    for (int kt = 0; kt <= qt; ++kt) {
        WAITV(0);   // own K(kt)+V(kt) DMA drained -> landed
        BAR();      // everyone's K(kt)+V(kt) visible; prev readers of buf[cur^1] done
        if (kt < qt) stage(kt + 1, cur ^ 1);

        const int co = cur * 512;
        const bool diag = (kt == qt);

        // ---- QK^T (swapped: A=K, B=Q -> D = S^T) ----
        f32x4 s4[4];
        #pragma unroll
        for (int j = 0; j < 4; ++j) s4[j] = zero;
        __builtin_amdgcn_s_setprio(1);
        #pragma unroll
        for (int j = 0; j < 4; ++j) {
            const int keyr = j * 16 + lx;
            const int rb = keyr * 8, sw = keyr & 7;
            #pragma unroll
            for (int d0 = 0; d0 < 2; ++d0) {
                const short8v kb = ((const short8v*)Ksh)[co + rb + ((hi4 + 4 * d0) ^ sw)];
                s4[j] = __builtin_amdgcn_mfma_f32_16x16x32_bf16(kb, qf[d0], s4[j], 0, 0, 0);
            }
        }
        __builtin_amdgcn_s_setprio(0);

        // ---- softmax (static M=0): lane holds P[key=j*16+hi4*4+r][q=lx] ----
        unsigned Wpk[4][2];   // [j][h]: bf16 pair of adjacent keys
        #pragma unroll
        for (int j = 0; j < 4; ++j) {
            float pv[4];
            #pragma unroll
            for (int r = 0; r < 4; ++r) {
                float e = __builtin_amdgcn_exp2f(s4[j][r]);
                if (diag && (j * 16 + hi4 * 4 + r) > (w * 16 + lx)) e = 0.f;
                lsum += e;
                pv[r] = e;
            }
            Wpk[j][0] = (unsigned)f2bf(pv[0]) | ((unsigned)f2bf(pv[1]) << 16);
            Wpk[j][1] = (unsigned)f2bf(pv[2]) | ((unsigned)f2bf(pv[3]) << 16);
        }
        // ---- in-register P transpose: 2-stage permlane butterfly ----
        #pragma unroll
        for (int j1 = 0; j1 < 2; ++j1)
            #pragma unroll
            for (int hh = 0; hh < 2; ++hh) {
                swap32(Wpk[2 * j1][hh], Wpk[2 * j1 + 1][hh]);
                swap16(Wpk[2 * j1][hh], Wpk[2 * j1 + 1][hh]);
            }
        short8v pa[2];
        #pragma unroll
        for (int k0 = 0; k0 < 2; ++k0) {
            u32x4 ah = {Wpk[2 * k0][0], Wpk[2 * k0][1], Wpk[2 * k0 + 1][0], Wpk[2 * k0 + 1][1]};
            pa[k0] = __builtin_bit_cast(short8v, ah);
        }

        // ---- PV (+ negated causal-ones on the diagonal tile); V(kt) already proven landed ----
        __builtin_amdgcn_s_setprio(1);
        #pragma unroll
        for (int dt = 0; dt < 4; ++dt) {
            const int drow = dt * 16 + lx;
            const int rb = drow * 8, sw = drow & 7;
            #pragma unroll
            for (int k0 = 0; k0 < 2; ++k0) {
                const short8v vb = ((const short8v*)Vsh)[co + rb + ((hi4 + 4 * k0) ^ sw)];
                y4[dt] = __builtin_amdgcn_mfma_f32_16x16x32_bf16(pa[k0], vb, y4[dt], 0, 0, 0);
                if (diag)
                    y4[dt] = __builtin_amdgcn_mfma_f32_16x16x32_bf16(nones[k0], vb, y4[dt], 0, 0, 0);
            }
        }
        __builtin_amdgcn_s_setprio(0);

        cur ^= 1;
    }

    // ---- l reduce: lsum is per-lane (q=lx); sum hi4 groups, redistribute to (hi4,r) ----
    lsum += __shfl_xor(lsum, 16);
    lsum += __shfl_xor(lsum, 32);
    float l4[4];
    #pragma unroll
    for (int r = 0; r < 4; ++r) l4[r] = __shfl(lsum, hi4 * 4 + r);

    // ---- masked-zero tail: y holds (PV - U); add suffix colsum, normalize ----
    #pragma unroll
    for (int dt = 0; dt < 4; ++dt) {
        const float st = stS[dt * 16 + lx];
        #pragma unroll
        for (int r = 0; r < 4; ++r) {
            const int t = qt * 64 + w * 16 + hi4 * 4 + r;
            const float linv = 1.f / (l4[r] + (float)(TT - 1 - t));
            const float yv = (y4[dt][r] + st) * linv;
            const size_t off = (size_t)(b * TT + t) * CC + h * HS + dt * 16 + lx;
            Yh[off] = f2bf(yv);
        }
    }
}

// ---------------- launch ----------------
extern "C" void kernel_launch(void* const* d_in, const int* in_sizes, int n_in,
                              void* d_out, int out_size, void* d_ws, size_t ws_size,
                              hipStream_t stream) {
    const float* x  = (const float*)d_in[0];
    const float* Wq = (const float*)d_in[1];
    const float* Wk = (const float*)d_in[2];
    const float* Wv = (const float*)d_in[3];
    const float* Wp = (const float*)d_in[4];
    float* out = (float*)d_out;

    char* ws = (char*)d_ws;
    // [0,8MB): x bf16; after qkv x is dead -> Y bf16
    u16* xh = (u16*)ws;
    u16* Yh = xh;
    // [16,24MB): Q bf16; [32,40MB): K bf16
    u16* Qh = (u16*)(ws + (16u << 20));
    u16* Kh = (u16*)(ws + (32u << 20));
    // [48,50MB): Wv bf16; [52,+256KB): TSg; [56,58MB): Wp bf16
    u16* wv = (u16*)(ws + (48u << 20));
    float* TSg = (float*)(ws + (52u << 20));
    u16* wp = (u16*)(ws + (56u << 20));
    // d_out (16MB): wqk [0,4MB), Vt [4,12MB) (both dead before proj overwrites)
    u16* wqk = (u16*)out;
    u16* Vth = (u16*)((char*)out + (4u << 20));

    fsplit_kernel<<<8192, 256, 0, stream>>>(x, Wq, Wk, Wv, Wp, xh, wqk, wv, wp);

    // merged QK GEMM (512 blocks) + V^T GEMM (256 blocks)
    qkv_kernel<<<768, 256, 0, stream>>>(xh, wqk, wv, Qh, Kh, Vth, TSg);

    attn_kernel<<<1024, 256, 0, stream>>>(Qh, Kh, Vth, TSg, Yh);

    // output projection, 128x128 tile, 256 equal blocks (overwrites d_out; wqk/Vt dead)
    gemm_proj<<<dim3(CC / 128, NROWS / 128), 256, 0, stream>>>(Yh, wp, out, NROWS, CC, CC);
}

// Round 14
// 101.511 us; speedup vs baseline: 1.1350x; 1.0291x over previous
//
#include <hip/hip_runtime.h>
#include <hip/hip_bf16.h>
#include <math.h>

#define BB 2
#define TT 2048
#define CC 1024
#define HH 16
#define HS 64
#define NROWS (BB * TT)   // 4096
#define QTILES (TT / 64)  // 32

typedef __attribute__((ext_vector_type(8))) short short8v;   // 8 bf16 (4 VGPRs)
typedef __attribute__((ext_vector_type(4))) float f32x4;
typedef __attribute__((ext_vector_type(4))) unsigned int u32x4;
typedef unsigned short u16;

__device__ __forceinline__ u16 f2bf(float f) {
    return __builtin_bit_cast(u16, (__bf16)f);   // RNE hw cvt
}

// async global->LDS, 16B/lane; LDS dest = wave-uniform base + lane*16
__device__ __forceinline__ void glds16(const void* g, void* l) {
    __builtin_amdgcn_global_load_lds((__attribute__((address_space(1))) void*)g,
                                     (__attribute__((address_space(3))) void*)l, 16, 0, 0);
}
#define WAITV(N) asm volatile("s_waitcnt vmcnt(" #N ")" ::: "memory")
#define BAR() do { __builtin_amdgcn_s_barrier(); __builtin_amdgcn_sched_barrier(0); } while (0)

// cross-lane half-swaps (gfx950): after swap32(a,b): a = {a.lo32, b.lo32}, b = {a.hi32, b.hi32}
__device__ __forceinline__ void swap32(unsigned& a, unsigned& b) {
    asm volatile("v_permlane32_swap_b32 %0, %1" : "+v"(a), "+v"(b));
}
__device__ __forceinline__ void swap16(unsigned& a, unsigned& b) {
    asm volatile("v_permlane16_swap_b32 %0, %1" : "+v"(a), "+v"(b));
}

// ---------------- fused cast: x + all 4 weight matrices -> bf16 (one launch) ----------------
__global__ __launch_bounds__(256) void fsplit_kernel(const float* __restrict__ x,
                                                     const float* __restrict__ Wq, const float* __restrict__ Wk,
                                                     const float* __restrict__ Wv, const float* __restrict__ Wp,
                                                     u16* __restrict__ xh,
                                                     u16* __restrict__ wqk,   // d_out: [Wq_h|Wk_h]
                                                     u16* __restrict__ wv, u16* __restrict__ wp) {
    const size_t WC = (size_t)CC * CC;
    const int bid = blockIdx.x;
    const float* src; u16* dh; float sc = 1.f; int i;
    if (bid < 4096) {            // x: 4M elements / 4 per thread
        src = x; dh = xh; i = bid * 256 + threadIdx.x;
    } else {
        const int wsel = (bid - 4096) >> 10;
        i = ((bid - 4096) & 1023) * 256 + threadIdx.x;
        // fold 1/8 AND log2(e) into Wq: attn softmax then uses a single v_exp_f32 (exp2)
        if (wsel == 0)      { src = Wq; dh = wqk;      sc = 0.125f * 1.4426950408889634f; }
        else if (wsel == 1) { src = Wk; dh = wqk + WC; }
        else if (wsel == 2) { src = Wv; dh = wv; }
        else                { src = Wp; dh = wp; }
    }
    float4 v = ((const float4*)src)[i];
    v.x *= sc; v.y *= sc; v.z *= sc; v.w *= sc;
    ushort4 H;
    H.x = f2bf(v.x); H.y = f2bf(v.y); H.z = f2bf(v.z); H.w = f2bf(v.w);
    ((ushort4*)dh)[i] = H;
}

// ---------------- merged QK + V^T GEMM (one launch, 768 equal 128x128 blocks) ----------------
// bid < 512:  QK GEMM  A=xh [4096xK], B=wqk [2048xK] -> Qh/Kh bf16 (stride CC)
// bid >= 512: V^T GEMM A=wv [1024xK], B=xh  [4096xK] -> Vt[bh][d][t] bf16 + colsum TSg
__global__ __launch_bounds__(256) void qkv_kernel(const u16* __restrict__ xh, const u16* __restrict__ wqk,
                                                  const u16* __restrict__ wv,
                                                  u16* __restrict__ Qo, u16* __restrict__ Ko,
                                                  u16* __restrict__ VtO, float* __restrict__ TSg) {
    __shared__ u16 lA[2 * 4096], lB[2 * 4096];
    const int tid = threadIdx.x;
    const int lane = tid & 63, w = tid >> 6;
    const int wr = w >> 1, wc = w & 1;
    const int fr = lane & 15, fc = lane >> 4;
    const int K = CC;

    const int gbid = blockIdx.x;
    const bool isQK = gbid < 512;
    const int sub = isQK ? gbid : gbid - 512;
    const int nbx = isQK ? 16 : 32;
    const int nwg = isQK ? 512 : 256;
    const u16* __restrict__ A = isQK ? xh : wv;
    const u16* __restrict__ B = isQK ? wqk : xh;

    const int swz = (sub & 7) * (nwg >> 3) + (sub >> 3);
    const int bm = (swz / nbx) * 128, bn = (swz % nbx) * 128;

    f32x4 acc[4][4];
    #pragma unroll
    for (int i = 0; i < 4; ++i)
        #pragma unroll
        for (int j = 0; j < 4; ++j) acc[i][j] = (f32x4){0.f, 0.f, 0.f, 0.f};

    const int lrow = lane >> 2, lcs = lane & 3;
    const int rA0 = w * 16 + lrow, rA1 = rA0 + 64;
    const size_t aoff0 = (size_t)(bm + rA0) * K + (lcs ^ ((rA0 >> 1) & 3)) * 8;
    const size_t aoff1 = (size_t)(bm + rA1) * K + (lcs ^ ((rA1 >> 1) & 3)) * 8;
    const size_t boff0 = (size_t)(bn + rA0) * K + (lcs ^ ((rA0 >> 1) & 3)) * 8;
    const size_t boff1 = (size_t)(bn + rA1) * K + (lcs ^ ((rA1 >> 1) & 3)) * 8;
    const int d0 = w * 512, d1 = 2048 + w * 512;

    int aslot[4], bslot[4];
    #pragma unroll
    for (int mi = 0; mi < 4; ++mi) {
        int row = wr * 64 + mi * 16 + fr;
        aslot[mi] = row * 4 + (fc ^ ((row >> 1) & 3));
    }
    #pragma unroll
    for (int ni = 0; ni < 4; ++ni) {
        int col = wc * 64 + ni * 16 + fr;
        bslot[ni] = col * 4 + (fc ^ ((col >> 1) & 3));
    }

    auto STAGE = [&](int t, int buf) {
        const int k0 = t * 32;
        const int bo = buf * 4096;
        glds16(A + aoff0 + k0, lA + bo + d0);
        glds16(A + aoff1 + k0, lA + bo + d1);
        glds16(B + boff0 + k0, lB + bo + d0);
        glds16(B + boff1 + k0, lB + bo + d1);
    };

    const int nt = K >> 5;
    STAGE(0, 0);

    #pragma unroll 2
    for (int t = 0; t < nt; ++t) {
        const int cur = t & 1;
        BAR();   // prev iter's readers of buf[cur^1] are done -> safe to overwrite
        if (t + 1 < nt) { STAGE(t + 1, cur ^ 1); WAITV(4); }
        else            { WAITV(0); }

        const int co = cur * 512;
        short8v fa[4], fb[4];
        #pragma unroll
        for (int mi = 0; mi < 4; ++mi) fa[mi] = ((const short8v*)lA)[co + aslot[mi]];
        #pragma unroll
        for (int ni = 0; ni < 4; ++ni) fb[ni] = ((const short8v*)lB)[co + bslot[ni]];
        __builtin_amdgcn_s_setprio(1);
        #pragma unroll
        for (int mi = 0; mi < 4; ++mi)
            #pragma unroll
            for (int ni = 0; ni < 4; ++ni)
                acc[mi][ni] = __builtin_amdgcn_mfma_f32_16x16x32_bf16(fa[mi], fb[ni], acc[mi][ni], 0, 0, 0);
        __builtin_amdgcn_s_setprio(0);
    }

    const int fq = lane >> 4;
    if (isQK) {
        #pragma unroll
        for (int mi = 0; mi < 4; ++mi)
            #pragma unroll
            for (int ni = 0; ni < 4; ++ni)
                #pragma unroll
                for (int r = 0; r < 4; ++r) {
                    const int rg = bm + wr * 64 + mi * 16 + fq * 4 + r;
                    const int cg = bn + wc * 64 + ni * 16 + fr;
                    const u16 hh = f2bf(acc[mi][ni][r]);
                    if (cg < CC) Qo[(size_t)rg * CC + cg] = hh;
                    else         Ko[(size_t)rg * CC + cg - CC] = hh;
                }
    } else {
        // Vt output: rg = h*64+d (row of Wv), cg = b*2048+t
        #pragma unroll
        for (int mi = 0; mi < 4; ++mi)
            #pragma unroll
            for (int ni = 0; ni < 4; ++ni)
                #pragma unroll
                for (int r = 0; r < 4; ++r) {
                    const int rg = bm + wr * 64 + mi * 16 + fq * 4 + r;
                    const int cg = bn + wc * 64 + ni * 16 + fr;
                    const int bq = cg >> 11, tq = cg & 2047;
                    const int hq = rg >> 6, dq = rg & 63;
                    VtO[((size_t)((bq << 4) + hq) * HS + dq) * TT + tq] = f2bf(acc[mi][ni][r]);
                }
        // per-qt column sums: wave wc covers qt = ((bn + wc*64)&2047)>>6
        __syncthreads();                 // all LDS frag reads done -> reuse lA
        float* TSL = (float*)lA;         // 256 floats: [wc][row 0..127]
        #pragma unroll
        for (int mi = 0; mi < 4; ++mi)
            #pragma unroll
            for (int r = 0; r < 4; ++r) {
                float s = acc[mi][0][r] + acc[mi][1][r] + acc[mi][2][r] + acc[mi][3][r];
                s += __shfl_xor(s, 1); s += __shfl_xor(s, 2);
                s += __shfl_xor(s, 4); s += __shfl_xor(s, 8);
                if (fr == 0) TSL[wc * 128 + wr * 64 + mi * 16 + fq * 4 + r] = s;
            }
        __syncthreads();
        {
            const int wcq = tid >> 7, row = tid & 127;
            const int col0 = bn + wcq * 64;
            const int bq = col0 >> 11, qtv = (col0 & 2047) >> 6;
            const int bhh = (bq << 4) + ((bm + row) >> 6);
            const int dq = (bm + row) & 63;
            TSg[((size_t)bhh * QTILES + qtv) * 64 + dq] = TSL[tid];
        }
    }
}

// ---------------- suffix scan over tile sums -> STile (diag-INCLUSIVE) ----------------
__global__ __launch_bounds__(64) void scan_kernel(const float* __restrict__ TSg,
                                                  float* __restrict__ STile) {
    const int bh = blockIdx.x;
    const int d = threadIdx.x;
    float s = 0.f;
    STile[((size_t)bh * 33 + 32) * 64 + d] = 0.f;
    for (int qt = QTILES - 1; qt >= 0; --qt) {
        s += TSg[((size_t)bh * QTILES + qt) * 64 + d];
        STile[((size_t)bh * 33 + qt) * 64 + d] = s;
    }
}

// ---------------- proj GEMM (bf16 in, fp32 out) ----------------
__global__ __launch_bounds__(256) void gemm_proj(const u16* __restrict__ A, const u16* __restrict__ B,
                                                 float* __restrict__ O, int M, int N, int K) {
    constexpr int GNT = 64;
    __shared__ u16 lA[2 * 4096], lB[2 * GNT * 32];
    const int tid = threadIdx.x;
    const int lane = tid & 63, w = tid >> 6;
    const int wr = w >> 1, wc = w & 1;
    const int fr = lane & 15, fc = lane >> 4;

    const int nbx = gridDim.x;
    const int bid = blockIdx.y * nbx + blockIdx.x;
    const int nwg = nbx * gridDim.y;
    const int swz = (bid & 7) * (nwg >> 3) + (bid >> 3);
    const int bm = (swz / nbx) * 128, bn = (swz % nbx) * GNT;

    f32x4 acc[4][2];
    #pragma unroll
    for (int i = 0; i < 4; ++i)
        #pragma unroll
        for (int j = 0; j < 2; ++j) acc[i][j] = (f32x4){0.f, 0.f, 0.f, 0.f};

    const int lrow = lane >> 2, lcs = lane & 3;
    const int rA0 = w * 16 + lrow, rA1 = rA0 + 64;
    const size_t aoff0 = (size_t)(bm + rA0) * K + (lcs ^ ((rA0 >> 1) & 3)) * 8;
    const size_t aoff1 = (size_t)(bm + rA1) * K + (lcs ^ ((rA1 >> 1) & 3)) * 8;
    const size_t boff0 = (size_t)(bn + rA0) * K + (lcs ^ ((rA0 >> 1) & 3)) * 8;
    const int d0 = w * 512, d1 = 2048 + w * 512;

    int aslot[4], bslot[2];
    #pragma unroll
    for (int mi = 0; mi < 4; ++mi) {
        int row = wr * 64 + mi * 16 + fr;
        aslot[mi] = row * 4 + (fc ^ ((row >> 1) & 3));
    }
    #pragma unroll
    for (int ni = 0; ni < 2; ++ni) {
        int col = wc * 32 + ni * 16 + fr;
        bslot[ni] = col * 4 + (fc ^ ((col >> 1) & 3));
    }

    auto STAGE = [&](int t, int buf) {
        const int k0 = t * 32;
        const int bo = buf * 4096;
        glds16(A + aoff0 + k0, lA + bo + d0);
        glds16(A + aoff1 + k0, lA + bo + d1);
        const int bo2 = buf * 2048;
        glds16(B + boff0 + k0, lB + bo2 + d0);
    };

    const int nt = K >> 5;
    STAGE(0, 0);

    #pragma unroll 2
    for (int t = 0; t < nt; ++t) {
        const int cur = t & 1;
        BAR();
        if (t + 1 < nt) { STAGE(t + 1, cur ^ 1); WAITV(3); }
        else            { WAITV(0); }

        const int co = cur * 512, co2 = cur * 256;
        short8v fa[4], fb[2];
        #pragma unroll
        for (int mi = 0; mi < 4; ++mi) fa[mi] = ((const short8v*)lA)[co + aslot[mi]];
        #pragma unroll
        for (int ni = 0; ni < 2; ++ni) fb[ni] = ((const short8v*)lB)[co2 + bslot[ni]];
        __builtin_amdgcn_s_setprio(1);
        #pragma unroll
        for (int mi = 0; mi < 4; ++mi)
            #pragma unroll
            for (int ni = 0; ni < 2; ++ni)
                acc[mi][ni] = __builtin_amdgcn_mfma_f32_16x16x32_bf16(fa[mi], fb[ni], acc[mi][ni], 0, 0, 0);
        __builtin_amdgcn_s_setprio(0);
    }

    const int fq = lane >> 4;
    #pragma unroll
    for (int mi = 0; mi < 4; ++mi)
        #pragma unroll
        for (int ni = 0; ni < 2; ++ni)
            #pragma unroll
            for (int r = 0; r < 4; ++r) {
                const int rg = bm + wr * 64 + mi * 16 + fq * 4 + r;
                const int cg = bn + wc * 32 + ni * 16 + fr;
                O[(size_t)rg * N + cg] = acc[mi][ni][r];
            }
}

// ---------------- MFMA flash attention (R6-PROVEN): 1 q-tile/block, K dbuf, V single-buf ----------------
// 1024 blocks = 32 bh x 32 qt; big qt dispatched first; bh locked to one XCD.
// 4 waves; wave w owns q-rows [w*16, w*16+16). Static max M=0; -U folded into y via
// negated causal ones MFMA on the diagonal tile; + STile at the end.
__global__ __launch_bounds__(256, 4) void attn_kernel(const u16* __restrict__ Qh,
                                                      const u16* __restrict__ Kh,
                                                      const u16* __restrict__ Vt,
                                                      const float* __restrict__ STile,
                                                      u16* __restrict__ Yh) {
    const int g = blockIdx.x;            // 1024
    const int bh = (g & 7) + 8 * ((g >> 3) & 3);   // bh locked to one XCD
    const int qt = 31 - (g >> 5);                  // big tiles first in dispatch order
    const int b = bh >> 4, h = bh & 15;
    const int tid = threadIdx.x;
    const int w = tid >> 6, lane = tid & 63;
    const int lx = lane & 15, hi4 = lane >> 4;

    __shared__ u16 Ksh[2 * 4096];   // 16KB: K dbuf
    __shared__ u16 Vsh[4096];       // 8KB: V single buffer

    const u16* Kg = Kh + (size_t)b * TT * CC + h * HS;
    const u16* Vg = Vt + (size_t)bh * HS * TT;

    // staging geometry: chunk s = w*64 + lane (+256); linear dest, source col pre-swizzled
    const int s0 = w * 64 + lane, s1 = 256 + w * 64 + lane;
    const int rr0 = s0 >> 3, gc0 = (s0 & 7) ^ (rr0 & 7);
    const int rr1 = s1 >> 3, gc1 = (s1 & 7) ^ (rr1 & 7);
    const int db0 = (w * 64) * 8, db1 = (256 + w * 64) * 8;
    const size_t kbase0 = (size_t)rr0 * CC + gc0 * 8;
    const size_t kbase1 = (size_t)rr1 * CC + gc1 * 8;
    const size_t vbase0 = (size_t)rr0 * TT + gc0 * 8;
    const size_t vbase1 = (size_t)rr1 * TT + gc1 * 8;

    auto stage_K = [&](int kt, int buf) {
        const size_t ko = (size_t)kt * 64 * CC;
        const int bo = buf * 4096;
        glds16(Kg + ko + kbase0, Ksh + bo + db0);
        glds16(Kg + ko + kbase1, Ksh + bo + db1);
    };
    auto stage_V = [&](int kt) {
        const int vo = kt * 64;
        glds16(Vg + vbase0 + vo, Vsh + db0);
        glds16(Vg + vbase1 + vo, Vsh + db1);
    };

    // NEGATED causal-inclusive ones A-frags (fold -U into y on the diagonal tile)
    short8v nones[2];
    #pragma unroll
    for (int k0 = 0; k0 < 2; ++k0)
        #pragma unroll
        for (int jj = 0; jj < 8; ++jj)
            nones[k0][jj] = (short)(((k0 * 32 + hi4 * 8 + jj) <= (w * 16 + lx)) ? 0xBF80 : 0);

    int cur = 0;
    stage_K(0, 0);

    const size_t qoff = (size_t)(b * TT + qt * 64 + w * 16 + lx) * CC + h * HS + hi4 * 8;
    short8v qf[2];
    qf[0] = *(const short8v*)(Qh + qoff); qf[1] = *(const short8v*)(Qh + qoff + 32);

    const f32x4 zero = {0.f, 0.f, 0.f, 0.f};
    f32x4 y4[4];
    float lsum = 0.f;
    #pragma unroll
    for (int dt = 0; dt < 4; ++dt) y4[dt] = zero;

    for (int kt = 0; kt <= qt; ++kt) {
        WAITV(0);   // own K(kt) (and V(kt-1)) drained -> landed
        BAR();      // everyone's K(kt) visible; prev PV readers of Vsh done
        stage_V(kt);
        if (kt < qt) stage_K(kt + 1, cur ^ 1);

        const int co = cur * 512;
        const bool diag = (kt == qt);

        // ---- QK^T (swapped: A=K, B=Q -> D = S^T) ----
        f32x4 s4[4];
        #pragma unroll
        for (int j = 0; j < 4; ++j) s4[j] = zero;
        __builtin_amdgcn_s_setprio(1);
        #pragma unroll
        for (int j = 0; j < 4; ++j) {
            const int keyr = j * 16 + lx;
            const int rb = keyr * 8, sw = keyr & 7;
            #pragma unroll
            for (int d0 = 0; d0 < 2; ++d0) {
                const short8v kb = ((const short8v*)Ksh)[co + rb + ((hi4 + 4 * d0) ^ sw)];
                s4[j] = __builtin_amdgcn_mfma_f32_16x16x32_bf16(kb, qf[d0], s4[j], 0, 0, 0);
            }
        }
        __builtin_amdgcn_s_setprio(0);

        // ---- softmax (static M=0): lane holds P[key=j*16+hi4*4+r][q=lx] ----
        unsigned Wpk[4][2];   // [j][h]: bf16 pair of adjacent keys
        #pragma unroll
        for (int j = 0; j < 4; ++j) {
            float pv[4];
            #pragma unroll
            for (int r = 0; r < 4; ++r) {
                float e = __builtin_amdgcn_exp2f(s4[j][r]);
                if (diag && (j * 16 + hi4 * 4 + r) > (w * 16 + lx)) e = 0.f;
                lsum += e;
                pv[r] = e;
            }
            Wpk[j][0] = (unsigned)f2bf(pv[0]) | ((unsigned)f2bf(pv[1]) << 16);
            Wpk[j][1] = (unsigned)f2bf(pv[2]) | ((unsigned)f2bf(pv[3]) << 16);
        }
        // ---- in-register P transpose: 2-stage permlane butterfly ----
        #pragma unroll
        for (int j1 = 0; j1 < 2; ++j1)
            #pragma unroll
            for (int hh = 0; hh < 2; ++hh) {
                swap32(Wpk[2 * j1][hh], Wpk[2 * j1 + 1][hh]);
                swap16(Wpk[2 * j1][hh], Wpk[2 * j1 + 1][hh]);
            }
        short8v pa[2];
        #pragma unroll
        for (int k0 = 0; k0 < 2; ++k0) {
            u32x4 ah = {Wpk[2 * k0][0], Wpk[2 * k0][1], Wpk[2 * k0 + 1][0], Wpk[2 * k0 + 1][1]};
            pa[k0] = __builtin_bit_cast(short8v, ah);
        }

        if (kt < qt) { WAITV(2); }   // drain V(kt); keep K(kt+1) in flight
        else         { WAITV(0); }
        BAR();   // everyone's V(kt) DMA landed -> Vsh complete

        // ---- PV (+ negated causal-ones on the diagonal tile) ----
        __builtin_amdgcn_s_setprio(1);
        #pragma unroll
        for (int dt = 0; dt < 4; ++dt) {
            const int drow = dt * 16 + lx;
            const int rb = drow * 8, sw = drow & 7;
            #pragma unroll
            for (int k0 = 0; k0 < 2; ++k0) {
                const short8v vb = ((const short8v*)Vsh)[rb + ((hi4 + 4 * k0) ^ sw)];
                y4[dt] = __builtin_amdgcn_mfma_f32_16x16x32_bf16(pa[k0], vb, y4[dt], 0, 0, 0);
                if (diag)
                    y4[dt] = __builtin_amdgcn_mfma_f32_16x16x32_bf16(nones[k0], vb, y4[dt], 0, 0, 0);
            }
        }
        __builtin_amdgcn_s_setprio(0);

        cur ^= 1;
    }

    // ---- l reduce: lsum is per-lane (q=lx); sum hi4 groups, redistribute to (hi4,r) ----
    lsum += __shfl_xor(lsum, 16);
    lsum += __shfl_xor(lsum, 32);
    float l4[4];
    #pragma unroll
    for (int r = 0; r < 4; ++r) l4[r] = __shfl(lsum, hi4 * 4 + r);

    // ---- masked-zero tail: y holds (PV - U); add STile, normalize ----
    const float* stp = STile + ((size_t)bh * 33 + qt) * 64;
    #pragma unroll
    for (int dt = 0; dt < 4; ++dt) {
        const float st = stp[dt * 16 + lx];
        #pragma unroll
        for (int r = 0; r < 4; ++r) {
            const int t = qt * 64 + w * 16 + hi4 * 4 + r;
            const float linv = 1.f / (l4[r] + (float)(TT - 1 - t));
            const float yv = (y4[dt][r] + st) * linv;
            const size_t off = (size_t)(b * TT + t) * CC + h * HS + dt * 16 + lx;
            Yh[off] = f2bf(yv);
        }
    }
}

// ---------------- launch ----------------
extern "C" void kernel_launch(void* const* d_in, const int* in_sizes, int n_in,
                              void* d_out, int out_size, void* d_ws, size_t ws_size,
                              hipStream_t stream) {
    const float* x  = (const float*)d_in[0];
    const float* Wq = (const float*)d_in[1];
    const float* Wk = (const float*)d_in[2];
    const float* Wv = (const float*)d_in[3];
    const float* Wp = (const float*)d_in[4];
    float* out = (float*)d_out;

    char* ws = (char*)d_ws;
    // [0,8MB): x bf16; after qkv x is dead -> Y bf16
    u16* xh = (u16*)ws;
    u16* Yh = xh;
    // [16,24MB): Q bf16; [32,40MB): K bf16
    u16* Qh = (u16*)(ws + (16u << 20));
    u16* Kh = (u16*)(ws + (32u << 20));
    // [48,50MB): Wv bf16; [52,+256KB): TSg; [56,58MB): Wp bf16
    u16* wv = (u16*)(ws + (48u << 20));
    float* TSg = (float*)(ws + (52u << 20));
    u16* wp = (u16*)(ws + (56u << 20));
    // [64MB,+270KB): STile
    float* St = (float*)(ws + (64u << 20));
    // d_out (16MB): wqk [0,4MB), Vt [4,12MB) (both dead before proj overwrites)
    u16* wqk = (u16*)out;
    u16* Vth = (u16*)((char*)out + (4u << 20));

    fsplit_kernel<<<8192, 256, 0, stream>>>(x, Wq, Wk, Wv, Wp, xh, wqk, wv, wp);

    // merged QK GEMM (512 blocks) + V^T GEMM (256 blocks)
    qkv_kernel<<<768, 256, 0, stream>>>(xh, wqk, wv, Qh, Kh, Vth, TSg);

    scan_kernel<<<BB * HH, 64, 0, stream>>>(TSg, St);

    attn_kernel<<<1024, 256, 0, stream>>>(Qh, Kh, Vth, St, Yh);

    // output projection (overwrites d_out; wqk/Vt dead)
    gemm_proj<<<dim3(CC / 64, NROWS / 128), 256, 0, stream>>>(Yh, wp, out, NROWS, CC, CC);
}